// Round 8
// baseline (125.300 us; speedup 1.0000x reference)
//
#include <hip/hip_runtime.h>

#define NN  50000
#define DEG 32
#define DF  128
#define DO  256
#define FEAT4 (NN * DF / 4)   // 1,600,000 float4 groups

typedef __bf16 bf16x8 __attribute__((ext_vector_type(8)));
typedef float  f32x4  __attribute__((ext_vector_type(4)));
typedef float  f32x2  __attribute__((ext_vector_type(2)));
typedef unsigned short u16x8 __attribute__((ext_vector_type(8)));

#if defined(__has_builtin)
#if __has_builtin(__builtin_amdgcn_cvt_pk_f32_fp8) && __has_builtin(__builtin_amdgcn_cvt_pk_fp8_f32)
#define HW_FP8 1
#endif
#endif
#ifndef HW_FP8
#define HW_FP8 0
#endif

__device__ __forceinline__ unsigned short f2bf(float f) {
    unsigned u = __float_as_uint(f);
    u += 0x7FFF + ((u >> 16) & 1);     // round-to-nearest-even
    return (unsigned short)(u >> 16);
}

#if !HW_FP8
__device__ __forceinline__ unsigned enc1_fp8(float f) {
    unsigned u = __float_as_uint(f);
    unsigned s = (u >> 31) << 7;
    float a = fabsf(f);
    if (!(a > 0.f)) return s;
    if (a >= 448.f) return s | 0x7E;
    u = __float_as_uint(a);
    int e = (int)((u >> 23) & 255) - 127;
    if (e < -6) {
        unsigned m = (unsigned)(a * 512.f + 0.5f);
        if (m >= 8) return s | 0x08;
        return s | m;
    }
    unsigned mant = (u >> 20) & 7;
    unsigned rnd  = ((u >> 19) & 1) & (((u & 0x7FFFF) != 0) | ((u >> 20) & 1));
    unsigned enc  = ((unsigned)(e + 7) << 3) | mant;
    return s | (enc + rnd);
}
__device__ __forceinline__ float dec1_fp8(unsigned b) {
    unsigned s = (b >> 7) & 1, e = (b >> 3) & 15, m = b & 7;
    float v = (e == 0) ? (float)m * 0.001953125f
                       : __uint_as_float(((e - 7 + 127) << 23) | (m << 20));
    return s ? -v : v;
}
#endif

__device__ __forceinline__ unsigned enc4_fp8(float4 v) {
#if HW_FP8
    int pk = 0;
    pk = __builtin_amdgcn_cvt_pk_fp8_f32(v.x, v.y, pk, false);
    pk = __builtin_amdgcn_cvt_pk_fp8_f32(v.z, v.w, pk, true);
    return (unsigned)pk;
#else
    return enc1_fp8(v.x) | (enc1_fp8(v.y) << 8) | (enc1_fp8(v.z) << 16) | (enc1_fp8(v.w) << 24);
#endif
}

// ---------------------------------------------------------------------------
// Convert: feat fp32 -> fp8 e4m3 gather table; W fp32 [K][N] -> Wt bf16 [N][K].
// ---------------------------------------------------------------------------
__global__ __launch_bounds__(256) void convert_kernel(
    const float* __restrict__ feat, const float* __restrict__ W,
    unsigned* __restrict__ feat8, unsigned short* __restrict__ Wt)
{
    const int gid = blockIdx.x * 256 + threadIdx.x;
    if (gid < FEAT4) {
        const float4 v = ((const float4*)feat)[gid];
        feat8[gid] = enc4_fp8(v);
    } else {
        const int t = gid - FEAT4;
        if (t < DO * DO) {
            const int n = t >> 8, k = t & 255;
            Wt[n * DO + k] = f2bf(W[k * DO + n]);   // write coalesced along k
        }
    }
}

// ---------------------------------------------------------------------------
// Aggregation (R0 verbatim, proven ~18 us): 16 nodes/block, 16 lanes/node x
// 8 B, fp32 accumulate, bf16 out. High TLP (800K threads).
// ---------------------------------------------------------------------------
__global__ __launch_bounds__(256) void agg_kernel(
    const unsigned* __restrict__ feat8,
    const int*      __restrict__ edges,
    unsigned short* __restrict__ aggb)
{
    const int node = blockIdx.x * 16 + (threadIdx.x >> 4);
    const int l    = threadIdx.x & 15;
    const int* e   = edges + node * DEG;

    float a[8] = {0.f, 0.f, 0.f, 0.f, 0.f, 0.f, 0.f, 0.f};
    #pragma unroll
    for (int d = 0; d < DEG; ++d) {
        const int idx = e[d];
        const uint2 pk = *(const uint2*)(feat8 + (size_t)idx * (DF / 4) + l * 2);
#if HW_FP8
        const f32x2 v0 = __builtin_amdgcn_cvt_pk_f32_fp8((int)pk.x, false);
        const f32x2 v1 = __builtin_amdgcn_cvt_pk_f32_fp8((int)pk.x, true);
        const f32x2 v2 = __builtin_amdgcn_cvt_pk_f32_fp8((int)pk.y, false);
        const f32x2 v3 = __builtin_amdgcn_cvt_pk_f32_fp8((int)pk.y, true);
        a[0] += v0[0]; a[1] += v0[1]; a[2] += v1[0]; a[3] += v1[1];
        a[4] += v2[0]; a[5] += v2[1]; a[6] += v3[0]; a[7] += v3[1];
#else
        #pragma unroll
        for (int j = 0; j < 4; ++j) a[j]     += dec1_fp8((pk.x >> (8 * j)) & 255);
        #pragma unroll
        for (int j = 0; j < 4; ++j) a[4 + j] += dec1_fp8((pk.y >> (8 * j)) & 255);
#endif
    }

    const float s = 1.0f / (float)DEG;
    u16x8 o;
    #pragma unroll
    for (int j = 0; j < 8; ++j) o[j] = f2bf(a[j] * s);
    *(u16x8*)(aggb + (size_t)node * DF + l * 8) = o;
}

// ---------------------------------------------------------------------------
// GEMM v8: v7 body + kc phase-stagger (start chunk = blockIdx & 3).
//  All 768 resident blocks previously staged/MFMA'd in lockstep -> HBM duty
//  ~60%. Independent K-chunks accumulate in any order, so staggering the
//  start phase keeps ~3/4 of blocks in MFMA while ~1/4 stage from HBM.
//  BM=64, BN=256, 512 threads = 8 waves 2m x 4n; LDT=72; LDS-transpose
//  epilogue with coalesced float4 stores (kept from v7, ~neutral).
// ---------------------------------------------------------------------------
#define BM  64
#define BN  256
#define LDT 72
#define LDP 68   // fp32 scratch row pitch

__global__ __launch_bounds__(512) void gemm_kernel(
    const float*          __restrict__ feat,
    const unsigned short* __restrict__ aggb,
    const unsigned short* __restrict__ Wt,
    float*                __restrict__ out)
{
    __shared__ __align__(16) unsigned short Asw[BM * LDT];   //  9.2 KB
    __shared__ __align__(16) unsigned short Bsw[BN * LDT];   // 36.9 KB

    const int tid = threadIdx.x;
    const int m0  = blockIdx.x * BM;

    const int wave = tid >> 6, lane = tid & 63;
    const int quad = lane >> 4, lr = lane & 15;
    const int wm   = (wave & 1) * 32;
    const int wn   = (wave >> 1) * 64;

    const int kstart = blockIdx.x & 3;   // phase stagger across blocks

    f32x4 acc[2][4] = {};

    for (int j = 0; j < 4; ++j) {
        const int kc = (kstart + j) & 3;

        if (j) __syncthreads();

        // A chunk: 64 rows x 64 cols, 1 seg/thread
        {
            const int r = tid >> 3;
            const int c = (tid & 7) * 8;
            int node = m0 + r;
            if (node >= NN) node = NN - 1;
            if (kc < 2) {
                const float* src = feat + (size_t)node * DF + kc * 64 + c;
                const float4 v0 = *(const float4*)(src);
                const float4 v1 = *(const float4*)(src + 4);
                u16x8 o;
                o[0] = f2bf(v0.x); o[1] = f2bf(v0.y); o[2] = f2bf(v0.z); o[3] = f2bf(v0.w);
                o[4] = f2bf(v1.x); o[5] = f2bf(v1.y); o[6] = f2bf(v1.z); o[7] = f2bf(v1.w);
                *(u16x8*)(Asw + r * LDT + c) = o;
            } else {
                *(u16x8*)(Asw + r * LDT + c) =
                    *(const u16x8*)(aggb + (size_t)node * DF + (kc - 2) * 64 + c);
            }
        }

        // B chunk: 256 rows x 64 cols from Wt (L2-resident), 4 segs/thread
        #pragma unroll
        for (int it = 0; it < 4; ++it) {
            const int sidx = it * 512 + tid;
            const int r = sidx >> 3;
            const int c = (sidx & 7) * 8;
            *(u16x8*)(Bsw + r * LDT + c) =
                *(const u16x8*)(Wt + (size_t)r * DO + kc * 64 + c);
        }

        __syncthreads();

        #pragma unroll
        for (int kk = 0; kk < 64; kk += 32) {
            const int kb = kk + quad * 8;
            bf16x8 af[2], bfr[4];
            #pragma unroll
            for (int i = 0; i < 2; ++i)
                af[i] = *(const bf16x8*)(Asw + (wm + i * 16 + lr) * LDT + kb);
            #pragma unroll
            for (int i = 0; i < 4; ++i)
                bfr[i] = *(const bf16x8*)(Bsw + (wn + i * 16 + lr) * LDT + kb);
            #pragma unroll
            for (int mi = 0; mi < 2; ++mi)
                #pragma unroll
                for (int ni = 0; ni < 4; ++ni)
                    acc[mi][ni] = __builtin_amdgcn_mfma_f32_16x16x32_bf16(
                        af[mi], bfr[ni], acc[mi][ni], 0, 0, 0);
        }
    }

    // ---- epilogue: relu + LDS transpose -> coalesced float4 stores
    __syncthreads();                         // all MFMA LDS reads done
    float* ws = (float*)Bsw + wave * (16 * LDP);   // 4352 B per wave

    #pragma unroll
    for (int mi = 0; mi < 2; ++mi) {
        #pragma unroll
        for (int ni = 0; ni < 4; ++ni)
            #pragma unroll
            for (int r = 0; r < 4; ++r)
                ws[(quad * 4 + r) * LDP + ni * 16 + lr] =
                    fmaxf(acc[mi][ni][r], 0.f);

        __syncthreads();                     // writes visible (also WAR fence)

        #pragma unroll
        for (int p = 0; p < 4; ++p) {
            const int row = p * 4 + (lane >> 4);   // 0..15
            const int cg  = (lane & 15) * 4;       // 0..60
            const float4 v = *(const float4*)(ws + row * LDP + cg);
            const int grow = m0 + wm + mi * 16 + row;
            if (grow < NN)
                *(float4*)(out + (size_t)grow * DO + wn + cg) = v;
        }

        __syncthreads();                     // before mi=1 overwrites scratch
    }
}

extern "C" void kernel_launch(void* const* d_in, const int* in_sizes, int n_in,
                              void* d_out, int out_size, void* d_ws, size_t ws_size,
                              hipStream_t stream)
{
    const float* feat  = (const float*)d_in[0];
    const int*   edges = (const int*)d_in[1];
    const float* W     = (const float*)d_in[2];
    float*       out   = (float*)d_out;

    unsigned short* aggb  = (unsigned short*)d_ws;                 // 12.8 MB
    unsigned*       feat8 = (unsigned*)(aggb + (size_t)NN * DF);   // 6.4 MB
    unsigned short* Wt    = (unsigned short*)(feat8 + (size_t)NN * DF / 4); // 128 KB

    convert_kernel<<<(FEAT4 + DO * DO + 255) / 256, 256, 0, stream>>>(
        feat, W, feat8, Wt);
    agg_kernel<<<NN / 16, 256, 0, stream>>>(feat8, edges, aggb);

    gemm_kernel<<<(NN + BM - 1) / BM, 512, 0, stream>>>(feat, aggb, Wt, out);
}

// Round 9
// 124.801 us; speedup vs baseline: 1.0040x; 1.0040x over previous
//
#include <hip/hip_runtime.h>

#define NN  50000
#define DEG 32
#define DF  128
#define DO  256
#define FEAT4 (NN * DF / 4)   // 1,600,000 float4 groups

typedef __bf16 bf16x8 __attribute__((ext_vector_type(8)));
typedef float  f32x4  __attribute__((ext_vector_type(4)));
typedef float  f32x2  __attribute__((ext_vector_type(2)));
typedef unsigned short u16x8 __attribute__((ext_vector_type(8)));

#if defined(__has_builtin)
#if __has_builtin(__builtin_amdgcn_cvt_pk_f32_fp8) && __has_builtin(__builtin_amdgcn_cvt_pk_fp8_f32)
#define HW_FP8 1
#endif
#endif
#ifndef HW_FP8
#define HW_FP8 0
#endif

__device__ __forceinline__ unsigned short f2bf(float f) {
    unsigned u = __float_as_uint(f);
    u += 0x7FFF + ((u >> 16) & 1);     // round-to-nearest-even
    return (unsigned short)(u >> 16);
}

#if !HW_FP8
__device__ __forceinline__ unsigned enc1_fp8(float f) {
    unsigned u = __float_as_uint(f);
    unsigned s = (u >> 31) << 7;
    float a = fabsf(f);
    if (!(a > 0.f)) return s;
    if (a >= 448.f) return s | 0x7E;
    u = __float_as_uint(a);
    int e = (int)((u >> 23) & 255) - 127;
    if (e < -6) {
        unsigned m = (unsigned)(a * 512.f + 0.5f);
        if (m >= 8) return s | 0x08;
        return s | m;
    }
    unsigned mant = (u >> 20) & 7;
    unsigned rnd  = ((u >> 19) & 1) & (((u & 0x7FFFF) != 0) | ((u >> 20) & 1));
    unsigned enc  = ((unsigned)(e + 7) << 3) | mant;
    return s | (enc + rnd);
}
__device__ __forceinline__ float dec1_fp8(unsigned b) {
    unsigned s = (b >> 7) & 1, e = (b >> 3) & 15, m = b & 7;
    float v = (e == 0) ? (float)m * 0.001953125f
                       : __uint_as_float(((e - 7 + 127) << 23) | (m << 20));
    return s ? -v : v;
}
#endif

__device__ __forceinline__ unsigned enc4_fp8(float4 v) {
#if HW_FP8
    int pk = 0;
    pk = __builtin_amdgcn_cvt_pk_fp8_f32(v.x, v.y, pk, false);
    pk = __builtin_amdgcn_cvt_pk_fp8_f32(v.z, v.w, pk, true);
    return (unsigned)pk;
#else
    return enc1_fp8(v.x) | (enc1_fp8(v.y) << 8) | (enc1_fp8(v.z) << 16) | (enc1_fp8(v.w) << 24);
#endif
}

// ---------------------------------------------------------------------------
// Convert: feat fp32 -> fp8 e4m3 gather table; W fp32 [K][N] -> Wt bf16 [N][K].
// ---------------------------------------------------------------------------
__global__ __launch_bounds__(256) void convert_kernel(
    const float* __restrict__ feat, const float* __restrict__ W,
    unsigned* __restrict__ feat8, unsigned short* __restrict__ Wt)
{
    const int gid = blockIdx.x * 256 + threadIdx.x;
    if (gid < FEAT4) {
        const float4 v = ((const float4*)feat)[gid];
        feat8[gid] = enc4_fp8(v);
    } else {
        const int t = gid - FEAT4;
        if (t < DO * DO) {
            const int n = t >> 8, k = t & 255;
            Wt[n * DO + k] = f2bf(W[k * DO + n]);   // write coalesced along k
        }
    }
}

// ---------------------------------------------------------------------------
// Aggregation (R0 verbatim, proven ~18 us): 16 nodes/block, 16 lanes/node x
// 8 B, fp32 accumulate, bf16 out. High TLP (800K threads).
// ---------------------------------------------------------------------------
__global__ __launch_bounds__(256) void agg_kernel(
    const unsigned* __restrict__ feat8,
    const int*      __restrict__ edges,
    unsigned short* __restrict__ aggb)
{
    const int node = blockIdx.x * 16 + (threadIdx.x >> 4);
    const int l    = threadIdx.x & 15;
    const int* e   = edges + node * DEG;

    float a[8] = {0.f, 0.f, 0.f, 0.f, 0.f, 0.f, 0.f, 0.f};
    #pragma unroll
    for (int d = 0; d < DEG; ++d) {
        const int idx = e[d];
        const uint2 pk = *(const uint2*)(feat8 + (size_t)idx * (DF / 4) + l * 2);
#if HW_FP8
        const f32x2 v0 = __builtin_amdgcn_cvt_pk_f32_fp8((int)pk.x, false);
        const f32x2 v1 = __builtin_amdgcn_cvt_pk_f32_fp8((int)pk.x, true);
        const f32x2 v2 = __builtin_amdgcn_cvt_pk_f32_fp8((int)pk.y, false);
        const f32x2 v3 = __builtin_amdgcn_cvt_pk_f32_fp8((int)pk.y, true);
        a[0] += v0[0]; a[1] += v0[1]; a[2] += v1[0]; a[3] += v1[1];
        a[4] += v2[0]; a[5] += v2[1]; a[6] += v3[0]; a[7] += v3[1];
#else
        #pragma unroll
        for (int j = 0; j < 4; ++j) a[j]     += dec1_fp8((pk.x >> (8 * j)) & 255);
        #pragma unroll
        for (int j = 0; j < 4; ++j) a[4 + j] += dec1_fp8((pk.y >> (8 * j)) & 255);
#endif
    }

    const float s = 1.0f / (float)DEG;
    u16x8 o;
    #pragma unroll
    for (int j = 0; j < 8; ++j) o[j] = f2bf(a[j] * s);
    *(u16x8*)(aggb + (size_t)node * DF + l * 8) = o;
}

// ---------------------------------------------------------------------------
// GEMM v9: 2-generation grid for read/write phase overlap.
//  BM=32, BN=256, 256 threads = 4 waves 1m x 4n (wave tile 32x64), grid=1563
//  = 2.03 generations at 3 blocks/CU (LDS 41.5 KB): generation-2 staging
//  reads overlap generation-1 epilogue writes (the 17us-read / 8us-write
//  chip-wide serialization was the 24-vs-14us gap; R7/R8 byte-level fixes
//  were neutral because they didn't change the time profile).
//  A read once (BN=256); B re-staged from L2-resident Wt (cheap); kc-stagger
//  kept; direct epilogue stores (proven equal to transpose in R7).
// ---------------------------------------------------------------------------
#define BM  32
#define BN  256
#define LDT 72

__global__ __launch_bounds__(256) void gemm_kernel(
    const float*          __restrict__ feat,
    const unsigned short* __restrict__ aggb,
    const unsigned short* __restrict__ Wt,
    float*                __restrict__ out)
{
    __shared__ __align__(16) unsigned short Asw[BM * LDT];   //  4.6 KB
    __shared__ __align__(16) unsigned short Bsw[BN * LDT];   // 36.9 KB

    const int tid = threadIdx.x;
    const int m0  = blockIdx.x * BM;

    const int wave = tid >> 6, lane = tid & 63;
    const int quad = lane >> 4, lr = lane & 15;
    const int wn   = wave * 64;

    const int kstart = blockIdx.x & 3;   // phase stagger across blocks

    f32x4 acc[2][4] = {};

    for (int j = 0; j < 4; ++j) {
        const int kc = (kstart + j) & 3;

        if (j) __syncthreads();

        // A chunk: 32 rows x 64 cols, 1 u16x8 per thread
        {
            const int r = tid >> 3;
            const int c = (tid & 7) * 8;
            int node = m0 + r;
            if (node >= NN) node = NN - 1;
            if (kc < 2) {
                const float* src = feat + (size_t)node * DF + kc * 64 + c;
                const float4 v0 = *(const float4*)(src);
                const float4 v1 = *(const float4*)(src + 4);
                u16x8 o;
                o[0] = f2bf(v0.x); o[1] = f2bf(v0.y); o[2] = f2bf(v0.z); o[3] = f2bf(v0.w);
                o[4] = f2bf(v1.x); o[5] = f2bf(v1.y); o[6] = f2bf(v1.z); o[7] = f2bf(v1.w);
                *(u16x8*)(Asw + r * LDT + c) = o;
            } else {
                *(u16x8*)(Asw + r * LDT + c) =
                    *(const u16x8*)(aggb + (size_t)node * DF + (kc - 2) * 64 + c);
            }
        }

        // B chunk: 256 rows x 64 cols from Wt (L2-resident), 8 segs/thread
        #pragma unroll
        for (int it = 0; it < 8; ++it) {
            const int sidx = it * 256 + tid;
            const int r = sidx >> 3;
            const int c = (sidx & 7) * 8;
            *(u16x8*)(Bsw + r * LDT + c) =
                *(const u16x8*)(Wt + (size_t)r * DO + kc * 64 + c);
        }

        __syncthreads();

        #pragma unroll
        for (int kk = 0; kk < 64; kk += 32) {
            const int kb = kk + quad * 8;
            bf16x8 af[2], bfr[4];
            #pragma unroll
            for (int i = 0; i < 2; ++i)
                af[i] = *(const bf16x8*)(Asw + (i * 16 + lr) * LDT + kb);
            #pragma unroll
            for (int i = 0; i < 4; ++i)
                bfr[i] = *(const bf16x8*)(Bsw + (wn + i * 16 + lr) * LDT + kb);
            #pragma unroll
            for (int mi = 0; mi < 2; ++mi)
                #pragma unroll
                for (int ni = 0; ni < 4; ++ni)
                    acc[mi][ni] = __builtin_amdgcn_mfma_f32_16x16x32_bf16(
                        af[mi], bfr[ni], acc[mi][ni], 0, 0, 0);
        }
    }

    // ---- epilogue: relu + direct stores (gen-2 staging overlaps these)
    #pragma unroll
    for (int mi = 0; mi < 2; ++mi) {
        #pragma unroll
        for (int r = 0; r < 4; ++r) {
            const int row = m0 + mi * 16 + quad * 4 + r;
            if (row < NN) {
                #pragma unroll
                for (int ni = 0; ni < 4; ++ni) {
                    out[(size_t)row * DO + wn + ni * 16 + lr] =
                        fmaxf(acc[mi][ni][r], 0.f);
                }
            }
        }
    }
}

extern "C" void kernel_launch(void* const* d_in, const int* in_sizes, int n_in,
                              void* d_out, int out_size, void* d_ws, size_t ws_size,
                              hipStream_t stream)
{
    const float* feat  = (const float*)d_in[0];
    const int*   edges = (const int*)d_in[1];
    const float* W     = (const float*)d_in[2];
    float*       out   = (float*)d_out;

    unsigned short* aggb  = (unsigned short*)d_ws;                 // 12.8 MB
    unsigned*       feat8 = (unsigned*)(aggb + (size_t)NN * DF);   // 6.4 MB
    unsigned short* Wt    = (unsigned short*)(feat8 + (size_t)NN * DF / 4); // 128 KB

    convert_kernel<<<(FEAT4 + DO * DO + 255) / 256, 256, 0, stream>>>(
        feat, W, feat8, Wt);
    agg_kernel<<<NN / 16, 256, 0, stream>>>(feat8, edges, aggb);

    gemm_kernel<<<(NN + BM - 1) / BM, 256, 0, stream>>>(feat, aggb, Wt, out);
}

// Round 10
// 123.964 us; speedup vs baseline: 1.0108x; 1.0067x over previous
//
#include <hip/hip_runtime.h>

#define NN  50000
#define DEG 32
#define DF  128
#define DO  256
#define FEAT4 (NN * DF / 4)   // 1,600,000 float4 groups

typedef __bf16 bf16x8 __attribute__((ext_vector_type(8)));
typedef float  f32x4  __attribute__((ext_vector_type(4)));
typedef float  f32x2  __attribute__((ext_vector_type(2)));
typedef unsigned short u16x8 __attribute__((ext_vector_type(8)));

#if defined(__has_builtin)
#if __has_builtin(__builtin_amdgcn_cvt_pk_f32_fp8) && __has_builtin(__builtin_amdgcn_cvt_pk_fp8_f32)
#define HW_FP8 1
#endif
#endif
#ifndef HW_FP8
#define HW_FP8 0
#endif

__device__ __forceinline__ unsigned short f2bf(float f) {
    unsigned u = __float_as_uint(f);
    u += 0x7FFF + ((u >> 16) & 1);     // round-to-nearest-even
    return (unsigned short)(u >> 16);
}

#if !HW_FP8
__device__ __forceinline__ unsigned enc1_fp8(float f) {
    unsigned u = __float_as_uint(f);
    unsigned s = (u >> 31) << 7;
    float a = fabsf(f);
    if (!(a > 0.f)) return s;
    if (a >= 448.f) return s | 0x7E;
    u = __float_as_uint(a);
    int e = (int)((u >> 23) & 255) - 127;
    if (e < -6) {
        unsigned m = (unsigned)(a * 512.f + 0.5f);
        if (m >= 8) return s | 0x08;
        return s | m;
    }
    unsigned mant = (u >> 20) & 7;
    unsigned rnd  = ((u >> 19) & 1) & (((u & 0x7FFFF) != 0) | ((u >> 20) & 1));
    unsigned enc  = ((unsigned)(e + 7) << 3) | mant;
    return s | (enc + rnd);
}
__device__ __forceinline__ float dec1_fp8(unsigned b) {
    unsigned s = (b >> 7) & 1, e = (b >> 3) & 15, m = b & 7;
    float v = (e == 0) ? (float)m * 0.001953125f
                       : __uint_as_float(((e - 7 + 127) << 23) | (m << 20));
    return s ? -v : v;
}
#endif

__device__ __forceinline__ unsigned enc4_fp8(float4 v) {
#if HW_FP8
    int pk = 0;
    pk = __builtin_amdgcn_cvt_pk_fp8_f32(v.x, v.y, pk, false);
    pk = __builtin_amdgcn_cvt_pk_fp8_f32(v.z, v.w, pk, true);
    return (unsigned)pk;
#else
    return enc1_fp8(v.x) | (enc1_fp8(v.y) << 8) | (enc1_fp8(v.z) << 16) | (enc1_fp8(v.w) << 24);
#endif
}

// async global->LDS, 16 B per lane (dest must be lane-linear: base + lane*16)
__device__ __forceinline__ void gload_lds16(const void* g, void* l) {
    __builtin_amdgcn_global_load_lds(
        (const __attribute__((address_space(1))) unsigned int*)g,
        (__attribute__((address_space(3))) unsigned int*)l, 16, 0, 0);
}

// ---------------------------------------------------------------------------
// Convert: feat fp32 -> fp8 e4m3 gather table; W fp32 [K][N] -> Wt bf16 [N][K].
// ---------------------------------------------------------------------------
__global__ __launch_bounds__(256) void convert_kernel(
    const float* __restrict__ feat, const float* __restrict__ W,
    unsigned* __restrict__ feat8, unsigned short* __restrict__ Wt)
{
    const int gid = blockIdx.x * 256 + threadIdx.x;
    if (gid < FEAT4) {
        const float4 v = ((const float4*)feat)[gid];
        feat8[gid] = enc4_fp8(v);
    } else {
        const int t = gid - FEAT4;
        if (t < DO * DO) {
            const int n = t >> 8, k = t & 255;
            Wt[n * DO + k] = f2bf(W[k * DO + n]);   // write coalesced along k
        }
    }
}

// ---------------------------------------------------------------------------
// Aggregation (R0 verbatim, proven ~18 us): 16 nodes/block, 16 lanes/node x
// 8 B, fp32 accumulate, bf16 out. High TLP (800K threads).
// ---------------------------------------------------------------------------
__global__ __launch_bounds__(256) void agg_kernel(
    const unsigned* __restrict__ feat8,
    const int*      __restrict__ edges,
    unsigned short* __restrict__ aggb)
{
    const int node = blockIdx.x * 16 + (threadIdx.x >> 4);
    const int l    = threadIdx.x & 15;
    const int* e   = edges + node * DEG;

    float a[8] = {0.f, 0.f, 0.f, 0.f, 0.f, 0.f, 0.f, 0.f};
    #pragma unroll
    for (int d = 0; d < DEG; ++d) {
        const int idx = e[d];
        const uint2 pk = *(const uint2*)(feat8 + (size_t)idx * (DF / 4) + l * 2);
#if HW_FP8
        const f32x2 v0 = __builtin_amdgcn_cvt_pk_f32_fp8((int)pk.x, false);
        const f32x2 v1 = __builtin_amdgcn_cvt_pk_f32_fp8((int)pk.x, true);
        const f32x2 v2 = __builtin_amdgcn_cvt_pk_f32_fp8((int)pk.y, false);
        const f32x2 v3 = __builtin_amdgcn_cvt_pk_f32_fp8((int)pk.y, true);
        a[0] += v0[0]; a[1] += v0[1]; a[2] += v1[0]; a[3] += v1[1];
        a[4] += v2[0]; a[5] += v2[1]; a[6] += v3[0]; a[7] += v3[1];
#else
        #pragma unroll
        for (int j = 0; j < 4; ++j) a[j]     += dec1_fp8((pk.x >> (8 * j)) & 255);
        #pragma unroll
        for (int j = 0; j < 4; ++j) a[4 + j] += dec1_fp8((pk.y >> (8 * j)) & 255);
#endif
    }

    const float s = 1.0f / (float)DEG;
    u16x8 o;
    #pragma unroll
    for (int j = 0; j < 8; ++j) o[j] = f2bf(a[j] * s);
    *(u16x8*)(aggb + (size_t)node * DF + l * 8) = o;
}

// ---------------------------------------------------------------------------
// GEMM v10: global_load_lds staging with both-sides XOR swizzle (T2 + #21).
//  BM=64, BN=256, 512 threads = 8 waves 2m x 4n (wave tile 32x64).
//  LDS linear [rows][64] bf16 (A 8KB, B 32KB -> 40KB, 4 blocks/CU).
//  Content swizzled at 16B-granule level: lds[r][s] = SRC[r][s ^ (r&7)].
//   - B (all kc) and A-agg (kc 2,3): global_load_lds width=16, dest byte
//     offset = tid*16 (lane-linear, required), SOURCE granule pre-swizzled.
//   - A-self (kc 0,1): reg-staged (needs f2bf), ds_write same swizzled slot.
//  MFMA-side read: addr = R*64 + ((G ^ (R&7))<<3) -> lanes 0..7 cover all 8
//  slots = all 32 banks (conflict-free), lanes 8..15 duplicate (2-way, free).
//  Staging loads now stay in flight until the pre-barrier vmcnt drain
//  instead of serializing per-thread through the VGPR round-trip.
// ---------------------------------------------------------------------------
#define BM  64
#define BN  256

__global__ __launch_bounds__(512) void gemm_kernel(
    const float*          __restrict__ feat,
    const unsigned short* __restrict__ aggb,
    const unsigned short* __restrict__ Wt,
    float*                __restrict__ out)
{
    __shared__ __align__(16) unsigned short Asw[BM * 64];    //  8 KB
    __shared__ __align__(16) unsigned short Bsw[BN * 64];    // 32 KB

    const int tid = threadIdx.x;
    const int m0  = blockIdx.x * BM;

    const int wave = tid >> 6, lane = tid & 63;
    const int quad = lane >> 4, lr = lane & 15;
    const int wm   = (wave & 1) * 32;
    const int wn   = (wave >> 1) * 64;

    const int kstart = blockIdx.x & 3;   // phase stagger across blocks

    // staging coords: thread -> (row r, granule slot s); A dest byte = tid*16
    const int r  = tid >> 3;             // 0..63
    const int s  = tid & 7;              // 0..7
    const int gsA = s ^ (r & 7);         // pre-swizzled source granule
    int nodeA = m0 + r;
    if (nodeA >= NN) nodeA = NN - 1;

    f32x4 acc[2][4] = {};

    for (int j = 0; j < 4; ++j) {
        const int kc = (kstart + j) & 3;

        if (j) __syncthreads();

        // ---- A chunk: 64 rows x 64 cols
        if (kc < 2) {
            const float* src = feat + (size_t)nodeA * DF + kc * 64 + gsA * 8;
            const float4 v0 = *(const float4*)(src);
            const float4 v1 = *(const float4*)(src + 4);
            u16x8 o;
            o[0] = f2bf(v0.x); o[1] = f2bf(v0.y); o[2] = f2bf(v0.z); o[3] = f2bf(v0.w);
            o[4] = f2bf(v1.x); o[5] = f2bf(v1.y); o[6] = f2bf(v1.z); o[7] = f2bf(v1.w);
            *(u16x8*)(Asw + r * 64 + s * 8) = o;
        } else {
            gload_lds16(aggb + (size_t)nodeA * DF + (kc - 2) * 64 + gsA * 8,
                        Asw + r * 64 + s * 8);
        }

        // ---- B chunk: 256 rows x 64 cols from Wt (L2-resident), 4/thread
        #pragma unroll
        for (int it = 0; it < 4; ++it) {
            const int sidx = it * 512 + tid;     // dest byte = sidx*16 (linear)
            const int br = sidx >> 3;
            const int bs = sidx & 7;
            const int gs = bs ^ (br & 7);
            gload_lds16(Wt + (size_t)br * DO + kc * 64 + gs * 8,
                        Bsw + br * 64 + bs * 8);
        }

        __syncthreads();   // compiler drains vmcnt(0)+lgkmcnt(0) here

        #pragma unroll
        for (int kk = 0; kk < 64; kk += 32) {
            const int G = (kk >> 3) + quad;      // granule index 0..7
            bf16x8 af[2], bfr[4];
            #pragma unroll
            for (int i = 0; i < 2; ++i) {
                const int R = wm + i * 16 + lr;
                af[i] = *(const bf16x8*)(Asw + R * 64 + ((G ^ (R & 7)) << 3));
            }
            #pragma unroll
            for (int i = 0; i < 4; ++i) {
                const int R = wn + i * 16 + lr;
                bfr[i] = *(const bf16x8*)(Bsw + R * 64 + ((G ^ (R & 7)) << 3));
            }
            #pragma unroll
            for (int mi = 0; mi < 2; ++mi)
                #pragma unroll
                for (int ni = 0; ni < 4; ++ni)
                    acc[mi][ni] = __builtin_amdgcn_mfma_f32_16x16x32_bf16(
                        af[mi], bfr[ni], acc[mi][ni], 0, 0, 0);
        }
    }

    // ---- epilogue: relu + direct stores
    #pragma unroll
    for (int mi = 0; mi < 2; ++mi) {
        #pragma unroll
        for (int rr = 0; rr < 4; ++rr) {
            const int row = m0 + wm + mi * 16 + quad * 4 + rr;
            if (row < NN) {
                #pragma unroll
                for (int ni = 0; ni < 4; ++ni) {
                    out[(size_t)row * DO + wn + ni * 16 + lr] =
                        fmaxf(acc[mi][ni][rr], 0.f);
                }
            }
        }
    }
}

extern "C" void kernel_launch(void* const* d_in, const int* in_sizes, int n_in,
                              void* d_out, int out_size, void* d_ws, size_t ws_size,
                              hipStream_t stream)
{
    const float* feat  = (const float*)d_in[0];
    const int*   edges = (const int*)d_in[1];
    const float* W     = (const float*)d_in[2];
    float*       out   = (float*)d_out;

    unsigned short* aggb  = (unsigned short*)d_ws;                 // 12.8 MB
    unsigned*       feat8 = (unsigned*)(aggb + (size_t)NN * DF);   // 6.4 MB
    unsigned short* Wt    = (unsigned short*)(feat8 + (size_t)NN * DF / 4); // 128 KB

    convert_kernel<<<(FEAT4 + DO * DO + 255) / 256, 256, 0, stream>>>(
        feat, W, feat8, Wt);
    agg_kernel<<<NN / 16, 256, 0, stream>>>(feat8, edges, aggb);

    gemm_kernel<<<(NN + BM - 1) / BM, 512, 0, stream>>>(feat, aggb, Wt, out);
}